// Round 6
// baseline (289.605 us; speedup 1.0000x reference)
//
#include <hip/hip_runtime.h>

// GlobalAttentionPooling: tensor_square_0e -> selu -> @W -> segment softmax -> weighted segment sum
// N nodes, 80 f32 ft (32 scalar + 16 x 3-vec), NG=1024 graphs (sorted batch_index), F=664.
//
// Math identities (validated rounds 1-4, absmax 3.9e-3):
//   selu const term cancels in softmax; pre-scale s by sqrt(log2e), v by sqrt(log2e/sqrt3)
//   so pair products are f*log2e -> exp2 directly. out_g = (sum nf*ex)/z_g.
//
// Round-11: OPERAND-RESIDENCY theory. Ledger: wall == VALUbusy + ~50us stall in r5(31+57)
//   and r10(62+48); stall invariant to code size/LDS layout/exp method; trans theory dead
//   (r10: +30us VALU work -> +22us wall, so v_exp wasn't the 57us). VGPR=32..40 in all
//   rounds but phase 1 needs >=50 live floats (s2=32+acc+W) -> compiler is folding loads
//   into uses, re-fetching s2 from global/L1 inside the loop, ~350cyc exposed per f2-iter.
//   Fix: (1) asm "+v" pin s2/vp once after build -- compiler may no longer remat from the
//   load, uses must come from registers; (2) scalar/vector halves loaded separately (peak
//   ~100 VGPR); (3) __launch_bounds__(320) w/o min-waves arg. v_exp kept (31us VALU floor).
//   Probe: VGPR_Count must jump to ~96+. Falsifier: VGPR high but main ~88 -> theory dead.

typedef float f2 __attribute__((ext_vector_type(2)));

#define C0 32
#define C1 16
#define NODE_F 80
#define NG_CONST 1024
#define NPB 320                 // nodes per block == threads per block (1 thread/node)
#define TPB 320

#define SELU_SCALE 1.0507009873554804934193349852946
#define SELU_ALPHA 1.6732632423543772848170429916717
#define LOG2E      1.4426950408889634073599246810019

#define CS_SCALE 1.2011224087864498f    // sqrt(log2e)
#define CV_SCALE 0.91271231102878545f   // sqrt(log2e/sqrt(3))

// ws float layout:
//   [0, 81920)        S accum: [1024 graphs][80 ch]
//   [81920, 82944)    z accum: [1024]
//   [82944, 84224)    Wpad: 512 f2 scalar-part rows (32x16) then 128 f2 vec-part rows (16x8)
#define WS_S 0
#define WS_Z 81920
#define WS_W 82944

__device__ __forceinline__ int ks_idx(int i, int j) { return i * C0 - (i * (i - 1)) / 2 + (j - i); }
__device__ __forceinline__ int kv_idx(int i, int j) { return 528 + i * C1 - (i * (i - 1)) / 2 + (j - i); }

// zero the accumulators + build padded W tables
__global__ __launch_bounds__(256) void prep_kernel(
    const float* __restrict__ W, float* __restrict__ ws)
{
    const int t = blockIdx.x * blockDim.x + threadIdx.x;
    if (t < 82944) {
        ws[t] = 0.0f;                       // S and z
    } else {
        int u = t - 82944;
        if (u < 512) {                      // Ws: i in [0,32), q in [0,16)
            int i = u >> 4, q = u & 15;
            int j0 = 2 * q, j1 = 2 * q + 1;
            ws[WS_W + 2 * u]     = (j0 >= i) ? W[ks_idx(i, j0)] : 0.0f;
            ws[WS_W + 2 * u + 1] = (j1 >= i) ? W[ks_idx(i, j1)] : 0.0f;
        } else if (u < 640) {               // Wv: i in [0,16), q in [0,8)
            int v = u - 512;
            int i = v >> 3, q = v & 7;
            int j0 = 2 * q, j1 = 2 * q + 1;
            ws[WS_W + 1024 + 2 * v]     = (j0 >= i) ? W[kv_idx(i, j0)] : 0.0f;
            ws[WS_W + 1024 + 2 * v + 1] = (j1 >= i) ? W[kv_idx(i, j1)] : 0.0f;
        }
    }
}

__global__ __launch_bounds__(TPB) void main_kernel(
    const float* __restrict__ nf, const int* __restrict__ bi,
    const float* __restrict__ ws, float* __restrict__ S,
    float* __restrict__ z, int N)
{
    __shared__ __align__(16) float Wlds[1280];
    __shared__ float exl[NPB];
    __shared__ int   bil[NPB];

    const int tid  = threadIdx.x;
    const int base = blockIdx.x * NPB;
    const float4* g4 = (const float4*)nf;

    #pragma unroll
    for (int u = tid; u < 1280; u += TPB) Wlds[u] = ws[WS_W + u];

    const int  n     = base + tid;
    const bool valid = (n < N);
    const int  nn    = valid ? n : (N - 1);
    bil[tid] = bi[nn];
    __syncthreads();                        // Wlds ready

    const float4* gp = g4 + (size_t)nn * 20;
    const f2* WsL = (const f2*)Wlds;          // 512 f2
    const f2* WvL = (const f2*)(Wlds + 1024); // 128 f2

    // ---- phase 1: scalar half -> s2 in REGISTERS (pinned) ----
    f2 s2[C0 / 2];
    {
        float4 rs[8];
        #pragma unroll
        for (int q = 0; q < 8; ++q) rs[q] = gp[q];
        #pragma unroll
        for (int q = 0; q < 8; ++q) {
            s2[2 * q]     = f2{rs[q].x, rs[q].y} * CS_SCALE;
            s2[2 * q + 1] = f2{rs[q].z, rs[q].w} * CS_SCALE;
        }
    }
    // Pin: "+v" marks each value as asm-modified -> compiler can no longer fold/remat
    // the global load into later uses; s2 must live in VGPRs from here on.
    #pragma unroll
    for (int q = 0; q < C0 / 2; ++q) asm volatile("" : "+v"(s2[q]));

    f2 accA[2], accB[2];
    accA[0] = (f2)0.f; accA[1] = (f2)0.f; accB[0] = (f2)0.f; accB[1] = (f2)0.f;

    // scalar triangle rows 0..15
    #pragma unroll
    for (int i = 0; i < 16; ++i) {
        const float si = (i & 1) ? s2[i >> 1].y : s2[i >> 1].x;
        const f2 si2 = f2{si, si};
        #pragma unroll
        for (int q = i >> 1; q < C0 / 2; ++q) {
            f2 f = si2 * s2[q];
            f2 p = __builtin_elementwise_max(f, (f2)0.f);
            f2 m = __builtin_elementwise_min(f, (f2)0.f);
            f2 e; e.x = __builtin_amdgcn_exp2f(m.x);
                  e.y = __builtin_amdgcn_exp2f(m.y);
            f2 w = WsL[i * 16 + q];             // broadcast ds_read_b64, pad slots = 0
            accA[q & 1] = __builtin_elementwise_fma(w, p, accA[q & 1]);
            accB[q & 1] = __builtin_elementwise_fma(w, e, accB[q & 1]);
        }
    }

    // issue vector-half global loads; rows 16..31 cover their HBM latency
    float4 rv[12];
    #pragma unroll
    for (int q = 0; q < 12; ++q) rv[q] = gp[8 + q];

    // scalar triangle rows 16..31
    #pragma unroll
    for (int i = 16; i < 32; ++i) {
        const float si = (i & 1) ? s2[i >> 1].y : s2[i >> 1].x;
        const f2 si2 = f2{si, si};
        #pragma unroll
        for (int q = i >> 1; q < C0 / 2; ++q) {
            f2 f = si2 * s2[q];
            f2 p = __builtin_elementwise_max(f, (f2)0.f);
            f2 m = __builtin_elementwise_min(f, (f2)0.f);
            f2 e; e.x = __builtin_amdgcn_exp2f(m.x);
                  e.y = __builtin_amdgcn_exp2f(m.y);
            f2 w = WsL[i * 16 + q];
            accA[q & 1] = __builtin_elementwise_fma(w, p, accA[q & 1]);
            accB[q & 1] = __builtin_elementwise_fma(w, e, accB[q & 1]);
        }
    }

    // vector part: build vp (pinned), then triangle
    f2 vp[C1 / 2][3];
    {
        const float* rvf = (const float*)rv;
        #pragma unroll
        for (int q = 0; q < C1 / 2; ++q) {
            #pragma unroll
            for (int c = 0; c < 3; ++c)
                vp[q][c] = f2{rvf[6 * q + c], rvf[6 * q + 3 + c]} * CV_SCALE;
        }
    }
    #pragma unroll
    for (int q = 0; q < C1 / 2; ++q) {
        asm volatile("" : "+v"(vp[q][0]));
        asm volatile("" : "+v"(vp[q][1]));
        asm volatile("" : "+v"(vp[q][2]));
    }

    #pragma unroll
    for (int i = 0; i < C1; ++i) {
        const int iq = i >> 1;
        const float vi0 = (i & 1) ? vp[iq][0].y : vp[iq][0].x;
        const float vi1 = (i & 1) ? vp[iq][1].y : vp[iq][1].x;
        const float vi2 = (i & 1) ? vp[iq][2].y : vp[iq][2].x;
        #pragma unroll
        for (int q = i >> 1; q < C1 / 2; ++q) {
            f2 f = vp[q][0] * f2{vi0, vi0};
            f = __builtin_elementwise_fma(vp[q][1], f2{vi1, vi1}, f);
            f = __builtin_elementwise_fma(vp[q][2], f2{vi2, vi2}, f);
            f2 p = __builtin_elementwise_max(f, (f2)0.f);
            f2 m = __builtin_elementwise_min(f, (f2)0.f);
            f2 e; e.x = __builtin_amdgcn_exp2f(m.x);
                  e.y = __builtin_amdgcn_exp2f(m.y);
            f2 w = WvL[i * 8 + q];
            accA[q & 1] = __builtin_elementwise_fma(w, p, accA[q & 1]);
            accB[q & 1] = __builtin_elementwise_fma(w, e, accB[q & 1]);
        }
    }

    const float A1 = accA[0].x + accA[0].y + accA[1].x + accA[1].y;
    const float A2 = accB[0].x + accB[0].y + accB[1].x + accB[1].y;
    const float l2 = fmaf((float)SELU_SCALE, A1,
                          (float)(SELU_SCALE * SELU_ALPHA * LOG2E) * A2);
    exl[tid] = valid ? __builtin_amdgcn_exp2f(l2) : 0.0f;
    __syncthreads();

    // ---- phase 2: thread (no, c4) sums 20 contiguous nodes' channel-group, flush per graph run ----
    const int no = tid / 20;       // 0..15
    const int c4 = tid % 20;
    int cg = bil[no * 20];
    float4 acc = make_float4(0.f, 0.f, 0.f, 0.f);
    float  zacc = 0.0f;

    #pragma unroll
    for (int k = 0; k < 20; ++k) {
        const int nl = no * 20 + k;
        const int g2 = bil[nl];
        if (g2 != cg) {
            unsafeAtomicAdd(&S[cg * NODE_F + c4 * 4 + 0], acc.x);
            unsafeAtomicAdd(&S[cg * NODE_F + c4 * 4 + 1], acc.y);
            unsafeAtomicAdd(&S[cg * NODE_F + c4 * 4 + 2], acc.z);
            unsafeAtomicAdd(&S[cg * NODE_F + c4 * 4 + 3], acc.w);
            if (c4 == 0) unsafeAtomicAdd(&z[cg], zacc);
            acc = make_float4(0.f, 0.f, 0.f, 0.f); zacc = 0.0f; cg = g2;
        }
        int idx = base + nl; if (idx > N - 1) idx = N - 1;   // pad nodes have w=0
        const float  w = exl[nl];
        const float4 v = g4[(size_t)idx * 20 + c4];
        acc.x = fmaf(v.x, w, acc.x); acc.y = fmaf(v.y, w, acc.y);
        acc.z = fmaf(v.z, w, acc.z); acc.w = fmaf(v.w, w, acc.w);
        zacc += w;
    }
    unsafeAtomicAdd(&S[cg * NODE_F + c4 * 4 + 0], acc.x);
    unsafeAtomicAdd(&S[cg * NODE_F + c4 * 4 + 1], acc.y);
    unsafeAtomicAdd(&S[cg * NODE_F + c4 * 4 + 2], acc.z);
    unsafeAtomicAdd(&S[cg * NODE_F + c4 * 4 + 3], acc.w);
    if (c4 == 0) unsafeAtomicAdd(&z[cg], zacc);
}

__global__ __launch_bounds__(256) void divide_kernel(
    const float* __restrict__ S, const float* __restrict__ z,
    float* __restrict__ out)
{
    const int t = blockIdx.x * blockDim.x + threadIdx.x;
    if (t >= NG_CONST * NODE_F) return;
    const float zz = z[t / NODE_F];
    out[t] = (zz > 0.0f) ? (S[t] / zz) : 0.0f;
}

extern "C" void kernel_launch(void* const* d_in, const int* in_sizes, int n_in,
                              void* d_out, int out_size, void* d_ws, size_t ws_size,
                              hipStream_t stream) {
    const float* nf = (const float*)d_in[0];   // (N, 80) f32
    const int*   bi = (const int*)d_in[1];     // (N,) i32 sorted
    // d_in[2] = num_graphs (static 1024)
    const float* W  = (const float*)d_in[3];   // (664,) f32
    float* out = (float*)d_out;

    const int N = in_sizes[0] / NODE_F;
    float* ws = (float*)d_ws;
    float* S  = ws + WS_S;
    float* z  = ws + WS_Z;

    hipLaunchKernelGGL(prep_kernel, dim3(332), dim3(256), 0, stream, W, ws);
    hipLaunchKernelGGL(main_kernel, dim3((N + NPB - 1) / NPB), dim3(TPB), 0, stream,
                       nf, bi, ws, S, z, N);
    hipLaunchKernelGGL(divide_kernel, dim3((NG_CONST * NODE_F + 255) / 256), dim3(256),
                       0, stream, S, z, out);
}

// Round 7
// 191.540 us; speedup vs baseline: 1.5120x; 1.5120x over previous
//
#include <hip/hip_runtime.h>

// GlobalAttentionPooling: tensor_square_0e -> selu -> @W -> segment softmax -> weighted segment sum
// N nodes, 80 f32 ft (32 scalar + 16 x 3-vec), NG=1024 graphs (sorted batch_index), F=664.
//
// Math identities (validated rounds 1-4, absmax 3.9e-3):
//   selu const term cancels in softmax; pre-scale s by sqrt(log2e), v by sqrt(log2e/sqrt3)
//   so pair products are f*log2e -> exp2 directly. out_g = (sum nf*ex)/z_g.
//
// Round-12: OPERAND-SINKING confirmed as the mechanism. r5 VGPR=36 but phase-1 live set is
//   ~90 floats -> compiler sinks row loads into the loop, re-fetching per-iter from global
//   (lane-divergent 64-line gathers, ~20KB/wave >> L1) = the structure-invariant ~50us stall.
//   r11 pins forced residency but collided at the allocator's 128 cap (s2 pins + rv staging
//   + vp pins ~136 live) -> 152MB scratch spill traffic (WRITE 20->173MB), VALU work
//   unchanged (31.8us == r5) -> wall 220. Fixes here:
//   (1) launch_bounds(128,4): VGPR cap 128 = 16-waves/CU tier; peak live ~100.
//   (2) Pin ONLY s2 (272/344 iters protected); vp unpinned (kills the 136-peak collision).
//   (3) TPB 128: 2344 blocks, 18.3 waves/CU continuous demand (r5 averaged 11.6) + finer tail.
//   Falsifiers: WRITE>30MB = spilled again; VGPR<=48 = pins ineffective; clean+still-88 = dead.

typedef float f2 __attribute__((ext_vector_type(2)));

#define C0 32
#define C1 16
#define NODE_F 80
#define NG_CONST 1024
#define NPB 128                 // nodes per block == threads per block (1 thread/node)
#define TPB 128
#define NCHUNK 6                // phase-2 node chunks (NCHUNK*20 <= TPB)

#define SELU_SCALE 1.0507009873554804934193349852946
#define SELU_ALPHA 1.6732632423543772848170429916717
#define LOG2E      1.4426950408889634073599246810019

#define CS_SCALE 1.2011224087864498f    // sqrt(log2e)
#define CV_SCALE 0.91271231102878545f   // sqrt(log2e/sqrt(3))

// ws float layout:
//   [0, 81920)        S accum: [1024 graphs][80 ch]
//   [81920, 82944)    z accum: [1024]
//   [82944, 84224)    Wpad: 512 f2 scalar-part rows (32x16) then 128 f2 vec-part rows (16x8)
#define WS_S 0
#define WS_Z 81920
#define WS_W 82944

__device__ __forceinline__ int ks_idx(int i, int j) { return i * C0 - (i * (i - 1)) / 2 + (j - i); }
__device__ __forceinline__ int kv_idx(int i, int j) { return 528 + i * C1 - (i * (i - 1)) / 2 + (j - i); }

// zero the accumulators + build padded W tables
__global__ __launch_bounds__(256) void prep_kernel(
    const float* __restrict__ W, float* __restrict__ ws)
{
    const int t = blockIdx.x * blockDim.x + threadIdx.x;
    if (t < 82944) {
        ws[t] = 0.0f;                       // S and z
    } else {
        int u = t - 82944;
        if (u < 512) {                      // Ws: i in [0,32), q in [0,16)
            int i = u >> 4, q = u & 15;
            int j0 = 2 * q, j1 = 2 * q + 1;
            ws[WS_W + 2 * u]     = (j0 >= i) ? W[ks_idx(i, j0)] : 0.0f;
            ws[WS_W + 2 * u + 1] = (j1 >= i) ? W[ks_idx(i, j1)] : 0.0f;
        } else if (u < 640) {               // Wv: i in [0,16), q in [0,8)
            int v = u - 512;
            int i = v >> 3, q = v & 7;
            int j0 = 2 * q, j1 = 2 * q + 1;
            ws[WS_W + 1024 + 2 * v]     = (j0 >= i) ? W[kv_idx(i, j0)] : 0.0f;
            ws[WS_W + 1024 + 2 * v + 1] = (j1 >= i) ? W[kv_idx(i, j1)] : 0.0f;
        }
    }
}

__global__ __launch_bounds__(TPB, 4) void main_kernel(
    const float* __restrict__ nf, const int* __restrict__ bi,
    const float* __restrict__ ws, float* __restrict__ S,
    float* __restrict__ z, int N)
{
    __shared__ __align__(16) float Wlds[1280];
    __shared__ float exl[NPB];
    __shared__ int   bil[NPB];

    const int tid  = threadIdx.x;
    const int base = blockIdx.x * NPB;
    const float4* g4 = (const float4*)nf;

    #pragma unroll
    for (int u = tid; u < 1280; u += TPB) Wlds[u] = ws[WS_W + u];

    const int  n     = base + tid;
    const bool valid = (n < N);
    const int  nn    = valid ? n : (N - 1);
    bil[tid] = bi[nn];
    __syncthreads();                        // Wlds + bil ready

    const float4* gp = g4 + (size_t)nn * 20;
    const f2* WsL = (const f2*)Wlds;          // 512 f2
    const f2* WvL = (const f2*)(Wlds + 1024); // 128 f2

    // ---- phase 1: scalar half -> s2 in registers, PINNED against load-sinking ----
    f2 s2[C0 / 2];
    {
        float4 rs[8];
        #pragma unroll
        for (int q = 0; q < 8; ++q) rs[q] = gp[q];
        #pragma unroll
        for (int q = 0; q < 8; ++q) {
            s2[2 * q]     = f2{rs[q].x, rs[q].y} * CS_SCALE;
            s2[2 * q + 1] = f2{rs[q].z, rs[q].w} * CS_SCALE;
        }
    }
    #pragma unroll
    for (int q = 0; q < C0 / 2; ++q) asm volatile("" : "+v"(s2[q]));

    f2 accA[2], accB[2];
    accA[0] = (f2)0.f; accA[1] = (f2)0.f; accB[0] = (f2)0.f; accB[1] = (f2)0.f;

    // scalar triangle rows 0..15
    #pragma unroll
    for (int i = 0; i < 16; ++i) {
        const float si = (i & 1) ? s2[i >> 1].y : s2[i >> 1].x;
        const f2 si2 = f2{si, si};
        #pragma unroll
        for (int q = i >> 1; q < C0 / 2; ++q) {
            f2 f = si2 * s2[q];
            f2 p = __builtin_elementwise_max(f, (f2)0.f);
            f2 m = __builtin_elementwise_min(f, (f2)0.f);
            f2 e; e.x = __builtin_amdgcn_exp2f(m.x);
                  e.y = __builtin_amdgcn_exp2f(m.y);
            f2 w = WsL[i * 16 + q];             // broadcast ds_read_b64, pad slots = 0
            accA[q & 1] = __builtin_elementwise_fma(w, p, accA[q & 1]);
            accB[q & 1] = __builtin_elementwise_fma(w, e, accB[q & 1]);
        }
    }

    // issue vector-half global loads; rows 16..31 cover their HBM latency
    float4 rv[12];
    #pragma unroll
    for (int q = 0; q < 12; ++q) rv[q] = gp[8 + q];

    // scalar triangle rows 16..31
    #pragma unroll
    for (int i = 16; i < 32; ++i) {
        const float si = (i & 1) ? s2[i >> 1].y : s2[i >> 1].x;
        const f2 si2 = f2{si, si};
        #pragma unroll
        for (int q = i >> 1; q < C0 / 2; ++q) {
            f2 f = si2 * s2[q];
            f2 p = __builtin_elementwise_max(f, (f2)0.f);
            f2 m = __builtin_elementwise_min(f, (f2)0.f);
            f2 e; e.x = __builtin_amdgcn_exp2f(m.x);
                  e.y = __builtin_amdgcn_exp2f(m.y);
            f2 w = WsL[i * 16 + q];
            accA[q & 1] = __builtin_elementwise_fma(w, p, accA[q & 1]);
            accB[q & 1] = __builtin_elementwise_fma(w, e, accB[q & 1]);
        }
    }

    // vector part: build vp (unpinned -- s2 is dead here, keep peak pressure low), triangle
    f2 vp[C1 / 2][3];
    {
        const float* rvf = (const float*)rv;
        #pragma unroll
        for (int q = 0; q < C1 / 2; ++q) {
            #pragma unroll
            for (int c = 0; c < 3; ++c)
                vp[q][c] = f2{rvf[6 * q + c], rvf[6 * q + 3 + c]} * CV_SCALE;
        }
    }

    #pragma unroll
    for (int i = 0; i < C1; ++i) {
        const int iq = i >> 1;
        const float vi0 = (i & 1) ? vp[iq][0].y : vp[iq][0].x;
        const float vi1 = (i & 1) ? vp[iq][1].y : vp[iq][1].x;
        const float vi2 = (i & 1) ? vp[iq][2].y : vp[iq][2].x;
        #pragma unroll
        for (int q = i >> 1; q < C1 / 2; ++q) {
            f2 f = vp[q][0] * f2{vi0, vi0};
            f = __builtin_elementwise_fma(vp[q][1], f2{vi1, vi1}, f);
            f = __builtin_elementwise_fma(vp[q][2], f2{vi2, vi2}, f);
            f2 p = __builtin_elementwise_max(f, (f2)0.f);
            f2 m = __builtin_elementwise_min(f, (f2)0.f);
            f2 e; e.x = __builtin_amdgcn_exp2f(m.x);
                  e.y = __builtin_amdgcn_exp2f(m.y);
            f2 w = WvL[i * 8 + q];
            accA[q & 1] = __builtin_elementwise_fma(w, p, accA[q & 1]);
            accB[q & 1] = __builtin_elementwise_fma(w, e, accB[q & 1]);
        }
    }

    const float A1 = accA[0].x + accA[0].y + accA[1].x + accA[1].y;
    const float A2 = accB[0].x + accB[0].y + accB[1].x + accB[1].y;
    const float l2 = fmaf((float)SELU_SCALE, A1,
                          (float)(SELU_SCALE * SELU_ALPHA * LOG2E) * A2);
    exl[tid] = valid ? __builtin_amdgcn_exp2f(l2) : 0.0f;
    __syncthreads();

    // ---- phase 2: thread (no, c4) sums a ~21-node chunk's channel-group, flush per graph run ----
    if (tid < NCHUNK * 20) {
        const int no = tid / 20;       // 0..5
        const int c4 = tid % 20;
        const int nb = (no * NPB) / NCHUNK;
        const int ne = ((no + 1) * NPB) / NCHUNK;
        int cg = bil[nb];
        float4 acc = make_float4(0.f, 0.f, 0.f, 0.f);
        float  zacc = 0.0f;

        for (int nl = nb; nl < ne; ++nl) {
            const int g2 = bil[nl];
            if (g2 != cg) {
                unsafeAtomicAdd(&S[cg * NODE_F + c4 * 4 + 0], acc.x);
                unsafeAtomicAdd(&S[cg * NODE_F + c4 * 4 + 1], acc.y);
                unsafeAtomicAdd(&S[cg * NODE_F + c4 * 4 + 2], acc.z);
                unsafeAtomicAdd(&S[cg * NODE_F + c4 * 4 + 3], acc.w);
                if (c4 == 0) unsafeAtomicAdd(&z[cg], zacc);
                acc = make_float4(0.f, 0.f, 0.f, 0.f); zacc = 0.0f; cg = g2;
            }
            int idx = base + nl; if (idx > N - 1) idx = N - 1;   // pad nodes have w=0
            const float  w = exl[nl];
            const float4 v = g4[(size_t)idx * 20 + c4];
            acc.x = fmaf(v.x, w, acc.x); acc.y = fmaf(v.y, w, acc.y);
            acc.z = fmaf(v.z, w, acc.z); acc.w = fmaf(v.w, w, acc.w);
            zacc += w;
        }
        unsafeAtomicAdd(&S[cg * NODE_F + c4 * 4 + 0], acc.x);
        unsafeAtomicAdd(&S[cg * NODE_F + c4 * 4 + 1], acc.y);
        unsafeAtomicAdd(&S[cg * NODE_F + c4 * 4 + 2], acc.z);
        unsafeAtomicAdd(&S[cg * NODE_F + c4 * 4 + 3], acc.w);
        if (c4 == 0) unsafeAtomicAdd(&z[cg], zacc);
    }
}

__global__ __launch_bounds__(256) void divide_kernel(
    const float* __restrict__ S, const float* __restrict__ z,
    float* __restrict__ out)
{
    const int t = blockIdx.x * blockDim.x + threadIdx.x;
    if (t >= NG_CONST * NODE_F) return;
    const float zz = z[t / NODE_F];
    out[t] = (zz > 0.0f) ? (S[t] / zz) : 0.0f;
}

extern "C" void kernel_launch(void* const* d_in, const int* in_sizes, int n_in,
                              void* d_out, int out_size, void* d_ws, size_t ws_size,
                              hipStream_t stream) {
    const float* nf = (const float*)d_in[0];   // (N, 80) f32
    const int*   bi = (const int*)d_in[1];     // (N,) i32 sorted
    // d_in[2] = num_graphs (static 1024)
    const float* W  = (const float*)d_in[3];   // (664,) f32
    float* out = (float*)d_out;

    const int N = in_sizes[0] / NODE_F;
    float* ws = (float*)d_ws;
    float* S  = ws + WS_S;
    float* z  = ws + WS_Z;

    hipLaunchKernelGGL(prep_kernel, dim3(332), dim3(256), 0, stream, W, ws);
    hipLaunchKernelGGL(main_kernel, dim3((N + NPB - 1) / NPB), dim3(TPB), 0, stream,
                       nf, bi, ws, S, z, N);
    hipLaunchKernelGGL(divide_kernel, dim3((NG_CONST * NODE_F + 255) / 256), dim3(256),
                       0, stream, S, z, out);
}